// Round 17
// baseline (2065.830 us; speedup 1.0000x reference)
//
#include <hip/hip_runtime.h>
#include <stdint.h>

#define BB 64
#define TT 256
#define VV 32000
#define DD 512
#define HH 1024
#define FH 4096

#define UCOL 1040                 // padded LDS col stride (i8, 1024+16)
#define ULDS (128 * UCOL)         // 133120
#define LSTM_LDS (ULDS + 1024)
#define RSTRIDE (TT * FH * 2)

typedef float f32x4 __attribute__((ext_vector_type(4)));
typedef int   i32x4 __attribute__((ext_vector_type(4)));
typedef __bf16 bf16x8 __attribute__((ext_vector_type(8)));

typedef __attribute__((address_space(1))) void void_g;
typedef __attribute__((address_space(3))) void void_l;

static __device__ __forceinline__ void gload_lds16(const void* g, void* l) {
  __builtin_amdgcn_global_load_lds((const void_g*)g, (void_l*)l, 16, 0, 0);
}

static __device__ __forceinline__ unsigned short f2bf(float f) {
  union { float f; unsigned u; } x; x.f = f;
  unsigned r = x.u + 0x7FFFu + ((x.u >> 16) & 1u);
  return (unsigned short)(r >> 16);
}
static __device__ __forceinline__ float bf2f(unsigned short s) {
  union { unsigned u; float f; } x; x.u = ((unsigned)s) << 16;
  return x.f;
}
static __device__ __forceinline__ i32x4 as_i32x4(uint4 v) {
  union { uint4 u; i32x4 i; } x; x.u = v; return x.i;
}
static __device__ __forceinline__ float sigm(float x) {
  return 1.f / (1.f + __expf(-x));
}
static __device__ __forceinline__ float tanh_f(float x) {
  x = fminf(15.f, fmaxf(-15.f, x));
  float e = __expf(2.f * x);
  return (e - 1.f) / (e + 1.f);
}

// ---------------- prep kernels ----------------

__global__ void k_cast_emb(const float* __restrict__ src, unsigned short* __restrict__ dst) {
  size_t i = ((size_t)blockIdx.x * 256 + threadIdx.x) * 8;
  float4 a = *(const float4*)(src + i);
  float4 b = *(const float4*)(src + i + 4);
  uint4 o;
  o.x = (unsigned)f2bf(a.x) | ((unsigned)f2bf(a.y) << 16);
  o.y = (unsigned)f2bf(a.z) | ((unsigned)f2bf(a.w) << 16);
  o.z = (unsigned)f2bf(b.x) | ((unsigned)f2bf(b.y) << 16);
  o.w = (unsigned)f2bf(b.z) | ((unsigned)f2bf(b.w) << 16);
  *(uint4*)(dst + i) = o;
}

// Plain transpose: Wt[n][k] bf16
__global__ void k_prep_w(const float* __restrict__ Wsrc, unsigned short* __restrict__ Wt) {
  int n = blockIdx.x;
  int k0 = threadIdx.x * 4;
  unsigned short q0 = f2bf(Wsrc[(size_t)(k0 + 0) * FH + n]);
  unsigned short q1 = f2bf(Wsrc[(size_t)(k0 + 1) * FH + n]);
  unsigned short q2 = f2bf(Wsrc[(size_t)(k0 + 2) * FH + n]);
  unsigned short q3 = f2bf(Wsrc[(size_t)(k0 + 3) * FH + n]);
  uint2 o;
  o.x = (unsigned)q0 | ((unsigned)q1 << 16);
  o.y = (unsigned)q2 | ((unsigned)q3 << 16);
  *(uint2*)((char*)Wt + (size_t)n * 1024 + (size_t)k0 * 2) = o;
}

// U int8 per-column quantization. Slice s (0..31), local col c (0..127):
// c = g*32 + m ; hidden = s*32 + m ; source col n = g*1024 + s*32 + m.
// Uq[s][c][k] i8 (col stride 1024), su[s*128+c] = maxcol / 127^2.
__global__ void k_prep_uq(const float* __restrict__ Usrc, char* __restrict__ Uq,
                          float* __restrict__ su) {
  __shared__ float red[4];
  int bid = blockIdx.x;
  int s = bid >> 7, c = bid & 127;
  int g = c >> 5, m = c & 31;
  int n = g * 1024 + s * 32 + m;
  int tid = threadIdx.x, lane = tid & 63, wid = tid >> 6;
  float v[4];
  float mx = 0.f;
  #pragma unroll
  for (int j = 0; j < 4; ++j) {
    v[j] = Usrc[(size_t)(tid * 4 + j) * FH + n];
    mx = fmaxf(mx, fabsf(v[j]));
  }
  #pragma unroll
  for (int off = 32; off; off >>= 1) mx = fmaxf(mx, __shfl_xor(mx, off));
  if (lane == 0) red[wid] = mx;
  __syncthreads();
  mx = fmaxf(fmaxf(red[0], red[1]), fmaxf(red[2], red[3]));
  float inv = mx > 0.f ? 127.f / mx : 0.f;
  unsigned pk = 0;
  #pragma unroll
  for (int j = 0; j < 4; ++j) {
    int q = __float2int_rn(v[j] * inv);
    pk |= ((unsigned)q & 255u) << (8 * j);
  }
  *(unsigned*)(Uq + (size_t)s * 131072 + (size_t)c * 1024 + tid * 4) = pk;
  if (tid == 0) su[s * 128 + c] = mx / 16129.f;
}

__global__ void k_mask(const int* __restrict__ tok, unsigned long long* __restrict__ mask64) {
  int t = threadIdx.x;
  unsigned long long m = 0;
  for (int b = 0; b < BB; ++b)
    m |= (unsigned long long)(tok[b * TT + t] != 0) << b;
  mask64[t] = m;
}

// ---------------- xW GEMM (gather fused) ----------------
// Output permuted: p = s*128 + m*4 + g  (4 gates adjacent per hidden)

__launch_bounds__(256)
__global__ void k_gemm_xw(const int* __restrict__ tok, const unsigned short* __restrict__ embb,
                          const unsigned short* __restrict__ Wt, const float* __restrict__ bsrc,
                          unsigned short* __restrict__ xw) {
  __shared__ char As[16384];
  __shared__ char Bs[16384];
  __shared__ int toks[128];
  int tid = threadIdx.x, lane = tid & 63, wid = tid >> 6;
  int bm = blockIdx.x >> 5, bn = blockIdx.x & 31;
  if (tid < 128) toks[tid] = tok[bm * 128 + tid];
  int wm = wid >> 1, wn = wid & 1;
  f32x4 vz = {0.f, 0.f, 0.f, 0.f};
  f32x4 acc[4][4];
  #pragma unroll
  for (int i = 0; i < 4; ++i)
    #pragma unroll
    for (int j = 0; j < 4; ++j) acc[i][j] = vz;

  int kls = (lane >> 4) * 16;
  for (int ks = 0; ks < 8; ++ks) {
    __syncthreads();
    #pragma unroll
    for (int c = 0; c < 4; ++c) {
      int o = wid * 4096 + c * 1024 + lane * 16;
      int m = o >> 7, kl = o & 127;
      const char* ga = (const char*)embb + (size_t)toks[m] * 1024 + ks * 128 + (kl ^ ((m & 7) << 4));
      gload_lds16(ga, As + o);
      const char* gb = (const char*)Wt + (size_t)(bn * 128 + m) * 1024 + ks * 128 + (kl ^ ((m & 7) << 4));
      gload_lds16(gb, Bs + o);
    }
    asm volatile("s_waitcnt vmcnt(0)" ::: "memory");
    __syncthreads();
    #pragma unroll
    for (int tk = 0; tk < 2; ++tk) {
      bf16x8 af[4], bf[4];
      int kb = tk * 64 + kls;
      #pragma unroll
      for (int mt = 0; mt < 4; ++mt) {
        int m = wm * 64 + mt * 16 + (lane & 15);
        af[mt] = *(const bf16x8*)(As + m * 128 + (kb ^ ((m & 7) << 4)));
      }
      #pragma unroll
      for (int nt = 0; nt < 4; ++nt) {
        int n = wn * 64 + nt * 16 + (lane & 15);
        bf[nt] = *(const bf16x8*)(Bs + n * 128 + (kb ^ ((n & 7) << 4)));
      }
      #pragma unroll
      for (int mt = 0; mt < 4; ++mt)
        #pragma unroll
        for (int nt = 0; nt < 4; ++nt)
          acc[mt][nt] = __builtin_amdgcn_mfma_f32_16x16x32_bf16(af[mt], bf[nt], acc[mt][nt], 0, 0, 0);
    }
  }
  #pragma unroll
  for (int nt = 0; nt < 4; ++nt) {
    int n = bn * 128 + wn * 64 + nt * 16 + (lane & 15);
    float bias = bsrc[n];
    int g = n >> 10, hid = n & 1023, s = hid >> 5, m = hid & 31;
    int p = s * 128 + m * 4 + g;
    #pragma unroll
    for (int mt = 0; mt < 4; ++mt) {
      #pragma unroll
      for (int r = 0; r < 4; ++r) {
        int row = bm * 128 + wm * 64 + mt * 16 + (lane >> 4) * 4 + r;
        xw[(size_t)row * FH + p] = f2bf(acc[mt][nt][r] + bias);
      }
    }
  }
}

// ---------------- persistent LSTM scan: 4 groups x 32 WGs ------------------
// R16 (padded per-flag cache lines) with ONE change: a single batched poll
// (each lane loads its own flag line -> 1 load covers the group's 64 flags),
// then all 16 h-loads issue at once (overlapped) and 16 MFMAs run.

#define GATE(R) do { \
  unsigned long long x_ = xg[R]; \
  float zi_ = (float)aI[R] * s0 + bf2f((unsigned short)(x_ & 0xFFFFu)); \
  float zf_ = (float)aF[R] * s1 + bf2f((unsigned short)((x_ >> 16) & 0xFFFFu)); \
  float zg_ = (float)aG[R] * s2 + bf2f((unsigned short)((x_ >> 32) & 0xFFFFu)); \
  float zo_ = (float)aO[R] * s3 + bf2f((unsigned short)((x_ >> 48) & 0xFFFFu)); \
  float I_ = sigm(zi_), F_ = sigm(zf_), G_ = tanh_f(zg_), O_ = sigm(zo_); \
  float cn_ = F_ * cst[R] + I_ * G_; \
  float hn_ = O_ * tanh_f(cn_); \
  if (!((mb >> (grp * 16 + lq * 4 + (R))) & 1ull)) { cn_ = cst[R]; hn_ = hst[R]; } \
  cst[R] = cn_; hst[R] = hn_; \
  hs[hh * 320 + (lq * 4 + (R)) * 20 + l15] = (char)__float2int_rn(hn_ * 127.f); \
  if (t == TT - 1) hfin[(size_t)(grp * 16 + lq * 4 + (R)) * 1024 + rank * 32 + hh * 16 + l15] = hn_; \
} while (0)

#define MFMA1(A, U) do { \
  i32x4 a_ = as_i32x4(A); \
  i32x4 b0_ = *(const i32x4*)(Us + bo0 + (U) * 64); \
  i32x4 b1_ = *(const i32x4*)(Us + bo1 + (U) * 64); \
  i32x4 b2_ = *(const i32x4*)(Us + bo2 + (U) * 64); \
  i32x4 b3_ = *(const i32x4*)(Us + bo3 + (U) * 64); \
  aI = __builtin_amdgcn_mfma_i32_16x16x64_i8(a_, b0_, aI, 0, 0, 0); \
  aF = __builtin_amdgcn_mfma_i32_16x16x64_i8(a_, b1_, aF, 0, 0, 0); \
  aG = __builtin_amdgcn_mfma_i32_16x16x64_i8(a_, b2_, aG, 0, 0, 0); \
  aO = __builtin_amdgcn_mfma_i32_16x16x64_i8(a_, b3_, aO, 0, 0, 0); \
} while (0)

__launch_bounds__(128, 1)
__global__ void k_lstm(const char* __restrict__ Uq, const float* __restrict__ su,
                       const unsigned short* __restrict__ xw,
                       const unsigned long long* __restrict__ mask64,
                       char* __restrict__ hseq, unsigned* __restrict__ flags,
                       float* __restrict__ hfin) {
  extern __shared__ char smem[];
  char* Us = smem;
  char* hs = smem + ULDS;   // [2 waves][16 rows][20]
  int tid = threadIdx.x, lane = tid & 63, hh = tid >> 6;
  int l15 = lane & 15, lq = lane >> 4;
  int grp = blockIdx.x >> 5, rank = blockIdx.x & 31;
  int m = hh * 16 + l15;    // hidden col within slice (0..31)

  // load U slice (i8) into padded LDS: 128 cols x 1024
  {
    const char* src = Uq + (size_t)rank * 131072;
    #pragma unroll 4
    for (int i = 0; i < 64; ++i) {
      int o = i * 2048 + tid * 16;
      int c = o >> 10, k = o & 1023;
      *(uint4*)(Us + c * UCOL + k) = *(const uint4*)(src + o);
    }
  }
  __syncthreads();

  float s0 = su[rank * 128 + 0 * 32 + m];
  float s1 = su[rank * 128 + 1 * 32 + m];
  float s2 = su[rank * 128 + 2 * 32 + m];
  float s3 = su[rank * 128 + 3 * 32 + m];
  int bo0 = (0 * 32 + m) * UCOL + lq * 16;
  int bo1 = (1 * 32 + m) * UCOL + lq * 16;
  int bo2 = (2 * 32 + m) * UCOL + lq * 16;
  int bo3 = (3 * 32 + m) * UCOL + lq * 16;

  float cst[4] = {0.f, 0.f, 0.f, 0.f};
  float hst[4] = {0.f, 0.f, 0.f, 0.f};

  const char* xb = (const char*)xw +
      ((size_t)(grp * 16 + lq * 4) * TT * FH + rank * 128 + m * 4) * 2;

  unsigned long long xg[4], xn[4];
  #pragma unroll
  for (int r = 0; r < 4; ++r) xg[r] = *(const unsigned long long*)(xb + (size_t)r * RSTRIDE);

  for (int t = 0; t < TT; ++t) {
    int tn = (t + 1) & 255;
    #pragma unroll
    for (int r = 0; r < 4; ++r)
      xn[r] = *(const unsigned long long*)(xb + (size_t)r * RSTRIDE + (size_t)tn * (FH * 2));
    unsigned long long mb = mask64[t];

    i32x4 aI = {0,0,0,0}, aF = {0,0,0,0}, aG = {0,0,0,0}, aO = {0,0,0,0};

    if (t > 0) {
      const unsigned* fl = flags + ((size_t)(t - 1) * 256 + grp * 64) * 16;
      const char* hp = hseq + (size_t)(t - 1) * 65536 + (size_t)(grp * 16 + l15) * 1024 + lq * 16;
      // ONE batched poll: lane covers flag `lane` (own 64B line)
      for (;;) {
        unsigned v = __hip_atomic_load(fl + (size_t)lane * 16,
                                       __ATOMIC_RELAXED, __HIP_MEMORY_SCOPE_AGENT);
        if (__all(v != 0)) break;
        __builtin_amdgcn_s_sleep(1);
      }
      asm volatile("" ::: "memory");
      uint4 A[16];
      #pragma unroll
      for (int u = 0; u < 16; ++u) A[u] = *(const uint4*)(hp + u * 64);
      #pragma unroll
      for (int u = 0; u < 16; ++u) { MFMA1(A[u], u); }
    }

    GATE(0); GATE(1); GATE(2); GATE(3);

    // pack wave's 16x16 i8 block and store (u32/lane) to the step buffer
    asm volatile("s_waitcnt lgkmcnt(0)" ::: "memory");
    {
      int prow = lane >> 2, pch = lane & 3;
      unsigned pv = *(const unsigned*)(hs + hh * 320 + prow * 20 + pch * 4);
      __hip_atomic_store(
          (unsigned*)(hseq + (size_t)t * 65536 + (size_t)(grp * 16 + prow) * 1024 +
                      rank * 32 + hh * 16 + pch * 4),
          pv, __ATOMIC_RELAXED, __HIP_MEMORY_SCOPE_AGENT);
    }
    asm volatile("s_waitcnt vmcnt(0)" ::: "memory");
    if (lane == 0)
      __hip_atomic_store(flags + ((size_t)t * 256 + grp * 64 + rank * 2 + hh) * 16, 1u,
                         __ATOMIC_RELAXED, __HIP_MEMORY_SCOPE_AGENT);

    xg[0] = xn[0]; xg[1] = xn[1]; xg[2] = xn[2]; xg[3] = xn[3];
  }
}

// ---------------- VAE head ----------------

__global__ void k_final(const float* __restrict__ hfin, const float* __restrict__ Wm,
                        const float* __restrict__ bm, const float* __restrict__ Wv,
                        const float* __restrict__ bv, const float* __restrict__ eps,
                        float* __restrict__ out) {
  int jb = blockIdx.x;
  int b = threadIdx.x & 63, u = threadIdx.x >> 6;
  int c0 = jb * 16 + u * 4;
  float am[4] = {0.f, 0.f, 0.f, 0.f};
  float av[4] = {0.f, 0.f, 0.f, 0.f};
  const float* hb = hfin + b * 1024;
  #pragma unroll 8
  for (int k = 0; k < 1024; ++k) {
    float hv = hb[k];
    float4 wm = *(const float4*)(Wm + (size_t)k * 1024 + c0);
    float4 wv = *(const float4*)(Wv + (size_t)k * 1024 + c0);
    am[0] += hv * wm.x; am[1] += hv * wm.y; am[2] += hv * wm.z; am[3] += hv * wm.w;
    av[0] += hv * wv.x; av[1] += hv * wv.y; av[2] += hv * wv.z; av[3] += hv * wv.w;
  }
  #pragma unroll
  for (int i = 0; i < 4; ++i) {
    int c = c0 + i;
    float mean = am[i] + bm[c];
    float lv = av[i] + bv[c];
    out[b * 1024 + c] = eps[b * 1024 + c] * __expf(0.5f * lv) + mean;
  }
}

// ---------------- launch ----------------

extern "C" void kernel_launch(void* const* d_in, const int* in_sizes, int n_in,
                              void* d_out, int out_size, void* d_ws, size_t ws_size,
                              hipStream_t stream) {
  const int*   tok = (const int*)d_in[0];
  const float* emb = (const float*)d_in[1];
  const float* W   = (const float*)d_in[2];
  const float* U   = (const float*)d_in[3];
  const float* bia = (const float*)d_in[4];
  const float* Wm  = (const float*)d_in[5];
  const float* bm  = (const float*)d_in[6];
  const float* Wv  = (const float*)d_in[7];
  const float* bv  = (const float*)d_in[8];
  const float* eps = (const float*)d_in[9];
  float* out = (float*)d_out;

  char* ws = (char*)d_ws;
  size_t off = 0;
  auto alloc = [&](size_t sz) { char* p = ws + off; off += (sz + 255) & ~(size_t)255; return p; };
  unsigned short* embb = (unsigned short*)alloc((size_t)VV * DD * 2);
  unsigned short* Wt   = (unsigned short*)alloc((size_t)FH * DD * 2);
  char*  Uq            = (char*)alloc((size_t)32 * 131072);
  float* su            = (float*)alloc((size_t)FH * 4);
  unsigned short* xw   = (unsigned short*)alloc((size_t)BB * TT * FH * 2);
  char*  hseq          = (char*)alloc((size_t)TT * 65536);
  unsigned* flags      = (unsigned*)alloc((size_t)TT * 256 * 64);
  unsigned long long* mask64 = (unsigned long long*)alloc((size_t)TT * 8);
  float* hfin          = (float*)alloc((size_t)BB * HH * 4);
  (void)in_sizes; (void)n_in; (void)out_size; (void)ws_size;

  (void)hipMemsetAsync(flags, 0, (size_t)TT * 256 * 64, stream);
  k_cast_emb<<<8000, 256, 0, stream>>>(emb, embb);
  k_prep_w<<<4096, 128, 0, stream>>>(W, Wt);
  k_prep_uq<<<4096, 256, 0, stream>>>(U, Uq, su);
  k_mask<<<1, 256, 0, stream>>>(tok, mask64);
  k_gemm_xw<<<4096, 256, 0, stream>>>(tok, embb, Wt, bia, xw);
  (void)hipFuncSetAttribute((const void*)k_lstm, hipFuncAttributeMaxDynamicSharedMemorySize, LSTM_LDS);
  k_lstm<<<128, 128, LSTM_LDS, stream>>>(Uq, su, xw, mask64, hseq, flags, hfin);
  k_final<<<64, 256, 0, stream>>>(hfin, Wm, bm, Wv, bv, eps, out);
}

// Round 18
// 1575.578 us; speedup vs baseline: 1.3112x; 1.3112x over previous
//
#include <hip/hip_runtime.h>
#include <stdint.h>

#define BB 64
#define TT 256
#define VV 32000
#define DD 512
#define HH 1024
#define FH 4096

#define UCOL 1040                 // padded LDS col stride (i8, 1024+16)
#define ULDS (128 * UCOL)         // 133120
#define LSTM_LDS (ULDS + 1024)
#define RSTRIDE (TT * FH * 2)

typedef float f32x4 __attribute__((ext_vector_type(4)));
typedef int   i32x4 __attribute__((ext_vector_type(4)));
typedef __bf16 bf16x8 __attribute__((ext_vector_type(8)));

typedef __attribute__((address_space(1))) void void_g;
typedef __attribute__((address_space(3))) void void_l;

static __device__ __forceinline__ void gload_lds16(const void* g, void* l) {
  __builtin_amdgcn_global_load_lds((const void_g*)g, (void_l*)l, 16, 0, 0);
}

static __device__ __forceinline__ unsigned short f2bf(float f) {
  union { float f; unsigned u; } x; x.f = f;
  unsigned r = x.u + 0x7FFFu + ((x.u >> 16) & 1u);
  return (unsigned short)(r >> 16);
}
static __device__ __forceinline__ float bf2f(unsigned short s) {
  union { unsigned u; float f; } x; x.u = ((unsigned)s) << 16;
  return x.f;
}
static __device__ __forceinline__ i32x4 as_i32x4(uint4 v) {
  union { uint4 u; i32x4 i; } x; x.u = v; return x.i;
}
static __device__ __forceinline__ float sigm(float x) {
  return 1.f / (1.f + __expf(-x));
}
static __device__ __forceinline__ float tanh_f(float x) {
  x = fminf(15.f, fmaxf(-15.f, x));
  float e = __expf(2.f * x);
  return (e - 1.f) / (e + 1.f);
}

// ---------------- prep kernels ----------------

__global__ void k_cast_emb(const float* __restrict__ src, unsigned short* __restrict__ dst) {
  size_t i = ((size_t)blockIdx.x * 256 + threadIdx.x) * 8;
  float4 a = *(const float4*)(src + i);
  float4 b = *(const float4*)(src + i + 4);
  uint4 o;
  o.x = (unsigned)f2bf(a.x) | ((unsigned)f2bf(a.y) << 16);
  o.y = (unsigned)f2bf(a.z) | ((unsigned)f2bf(a.w) << 16);
  o.z = (unsigned)f2bf(b.x) | ((unsigned)f2bf(b.y) << 16);
  o.w = (unsigned)f2bf(b.z) | ((unsigned)f2bf(b.w) << 16);
  *(uint4*)(dst + i) = o;
}

// LDS tile transpose: Wt[n][k] bf16. 64x64 tiles, coalesced read+write.
__launch_bounds__(256)
__global__ void k_prep_w(const float* __restrict__ Wsrc, unsigned short* __restrict__ Wt) {
  __shared__ float tile[64 * 68];
  int kb = blockIdx.x >> 6;     // k block (0..7)
  int nb = blockIdx.x & 63;     // n block (0..63)
  int tid = threadIdx.x;
  int r = tid >> 4;             // 0..15
  int c4 = (tid & 15) * 4;
  #pragma unroll
  for (int i = 0; i < 4; ++i) {
    int k = r + i * 16;
    float4 v = *(const float4*)(Wsrc + (size_t)(kb * 64 + k) * FH + nb * 64 + c4);
    *(float4*)&tile[k * 68 + c4] = v;
  }
  __syncthreads();
  int nr = tid >> 2;            // 0..63
  int kc = (tid & 3) * 16;      // 0,16,32,48
  unsigned o[8];
  #pragma unroll
  for (int h = 0; h < 8; ++h) {
    unsigned short e0 = f2bf(tile[(kc + 2 * h) * 68 + nr]);
    unsigned short e1 = f2bf(tile[(kc + 2 * h + 1) * 68 + nr]);
    o[h] = (unsigned)e0 | ((unsigned)e1 << 16);
  }
  uint4* dst = (uint4*)((char*)Wt + (size_t)(nb * 64 + nr) * 1024 + (size_t)(kb * 64 + kc) * 2);
  dst[0] = make_uint4(o[0], o[1], o[2], o[3]);
  dst[1] = make_uint4(o[4], o[5], o[6], o[7]);
}

// U int8 per-column quantization. Slice s (0..31), local col c (0..127):
// c = g*32 + m ; hidden = s*32 + m ; source col n = g*1024 + s*32 + m.
// Uq[s][c][k] i8 (col stride 1024), su[s*128+c] = maxcol / 127^2.
__global__ void k_prep_uq(const float* __restrict__ Usrc, char* __restrict__ Uq,
                          float* __restrict__ su) {
  __shared__ float red[4];
  int bid = blockIdx.x;
  int s = bid >> 7, c = bid & 127;
  int g = c >> 5, m = c & 31;
  int n = g * 1024 + s * 32 + m;
  int tid = threadIdx.x, lane = tid & 63, wid = tid >> 6;
  float v[4];
  float mx = 0.f;
  #pragma unroll
  for (int j = 0; j < 4; ++j) {
    v[j] = Usrc[(size_t)(tid * 4 + j) * FH + n];
    mx = fmaxf(mx, fabsf(v[j]));
  }
  #pragma unroll
  for (int off = 32; off; off >>= 1) mx = fmaxf(mx, __shfl_xor(mx, off));
  if (lane == 0) red[wid] = mx;
  __syncthreads();
  mx = fmaxf(fmaxf(red[0], red[1]), fmaxf(red[2], red[3]));
  float inv = mx > 0.f ? 127.f / mx : 0.f;
  unsigned pk = 0;
  #pragma unroll
  for (int j = 0; j < 4; ++j) {
    int q = __float2int_rn(v[j] * inv);
    pk |= ((unsigned)q & 255u) << (8 * j);
  }
  *(unsigned*)(Uq + (size_t)s * 131072 + (size_t)c * 1024 + tid * 4) = pk;
  if (tid == 0) su[s * 128 + c] = mx / 16129.f;
}

__global__ void k_mask(const int* __restrict__ tok, unsigned long long* __restrict__ mask64) {
  int t = threadIdx.x;
  unsigned long long m = 0;
  for (int b = 0; b < BB; ++b)
    m |= (unsigned long long)(tok[b * TT + t] != 0) << b;
  mask64[t] = m;
}

// ---------------- xW GEMM (gather fused) ----------------
// Output permuted: p = s*128 + m*4 + g  (4 gates adjacent per hidden)

__launch_bounds__(256)
__global__ void k_gemm_xw(const int* __restrict__ tok, const unsigned short* __restrict__ embb,
                          const unsigned short* __restrict__ Wt, const float* __restrict__ bsrc,
                          unsigned short* __restrict__ xw) {
  __shared__ char As[16384];
  __shared__ char Bs[16384];
  __shared__ int toks[128];
  int tid = threadIdx.x, lane = tid & 63, wid = tid >> 6;
  int bm = blockIdx.x >> 5, bn = blockIdx.x & 31;
  if (tid < 128) toks[tid] = tok[bm * 128 + tid];
  int wm = wid >> 1, wn = wid & 1;
  f32x4 vz = {0.f, 0.f, 0.f, 0.f};
  f32x4 acc[4][4];
  #pragma unroll
  for (int i = 0; i < 4; ++i)
    #pragma unroll
    for (int j = 0; j < 4; ++j) acc[i][j] = vz;

  int kls = (lane >> 4) * 16;
  for (int ks = 0; ks < 8; ++ks) {
    __syncthreads();
    #pragma unroll
    for (int c = 0; c < 4; ++c) {
      int o = wid * 4096 + c * 1024 + lane * 16;
      int m = o >> 7, kl = o & 127;
      const char* ga = (const char*)embb + (size_t)toks[m] * 1024 + ks * 128 + (kl ^ ((m & 7) << 4));
      gload_lds16(ga, As + o);
      const char* gb = (const char*)Wt + (size_t)(bn * 128 + m) * 1024 + ks * 128 + (kl ^ ((m & 7) << 4));
      gload_lds16(gb, Bs + o);
    }
    asm volatile("s_waitcnt vmcnt(0)" ::: "memory");
    __syncthreads();
    #pragma unroll
    for (int tk = 0; tk < 2; ++tk) {
      bf16x8 af[4], bf[4];
      int kb = tk * 64 + kls;
      #pragma unroll
      for (int mt = 0; mt < 4; ++mt) {
        int m = wm * 64 + mt * 16 + (lane & 15);
        af[mt] = *(const bf16x8*)(As + m * 128 + (kb ^ ((m & 7) << 4)));
      }
      #pragma unroll
      for (int nt = 0; nt < 4; ++nt) {
        int n = wn * 64 + nt * 16 + (lane & 15);
        bf[nt] = *(const bf16x8*)(Bs + n * 128 + (kb ^ ((n & 7) << 4)));
      }
      #pragma unroll
      for (int mt = 0; mt < 4; ++mt)
        #pragma unroll
        for (int nt = 0; nt < 4; ++nt)
          acc[mt][nt] = __builtin_amdgcn_mfma_f32_16x16x32_bf16(af[mt], bf[nt], acc[mt][nt], 0, 0, 0);
    }
  }
  #pragma unroll
  for (int nt = 0; nt < 4; ++nt) {
    int n = bn * 128 + wn * 64 + nt * 16 + (lane & 15);
    float bias = bsrc[n];
    int g = n >> 10, hid = n & 1023, s = hid >> 5, m = hid & 31;
    int p = s * 128 + m * 4 + g;
    #pragma unroll
    for (int mt = 0; mt < 4; ++mt) {
      #pragma unroll
      for (int r = 0; r < 4; ++r) {
        int row = bm * 128 + wm * 64 + mt * 16 + (lane >> 4) * 4 + r;
        xw[(size_t)row * FH + p] = f2bf(acc[mt][nt][r] + bias);
      }
    }
  }
}

// ---------------- persistent LSTM scan: 4 groups x 32 WGs ------------------
// Padded per-flag cache lines + single batched poll (lane = own flag line),
// then all 16 h-loads issue at once and 16 i8 MFMAs run. (Best: R17 k_lstm.)

#define GATE(R) do { \
  unsigned long long x_ = xg[R]; \
  float zi_ = (float)aI[R] * s0 + bf2f((unsigned short)(x_ & 0xFFFFu)); \
  float zf_ = (float)aF[R] * s1 + bf2f((unsigned short)((x_ >> 16) & 0xFFFFu)); \
  float zg_ = (float)aG[R] * s2 + bf2f((unsigned short)((x_ >> 32) & 0xFFFFu)); \
  float zo_ = (float)aO[R] * s3 + bf2f((unsigned short)((x_ >> 48) & 0xFFFFu)); \
  float I_ = sigm(zi_), F_ = sigm(zf_), G_ = tanh_f(zg_), O_ = sigm(zo_); \
  float cn_ = F_ * cst[R] + I_ * G_; \
  float hn_ = O_ * tanh_f(cn_); \
  if (!((mb >> (grp * 16 + lq * 4 + (R))) & 1ull)) { cn_ = cst[R]; hn_ = hst[R]; } \
  cst[R] = cn_; hst[R] = hn_; \
  hs[hh * 320 + (lq * 4 + (R)) * 20 + l15] = (char)__float2int_rn(hn_ * 127.f); \
  if (t == TT - 1) hfin[(size_t)(grp * 16 + lq * 4 + (R)) * 1024 + rank * 32 + hh * 16 + l15] = hn_; \
} while (0)

#define MFMA1(A, U) do { \
  i32x4 a_ = as_i32x4(A); \
  i32x4 b0_ = *(const i32x4*)(Us + bo0 + (U) * 64); \
  i32x4 b1_ = *(const i32x4*)(Us + bo1 + (U) * 64); \
  i32x4 b2_ = *(const i32x4*)(Us + bo2 + (U) * 64); \
  i32x4 b3_ = *(const i32x4*)(Us + bo3 + (U) * 64); \
  aI = __builtin_amdgcn_mfma_i32_16x16x64_i8(a_, b0_, aI, 0, 0, 0); \
  aF = __builtin_amdgcn_mfma_i32_16x16x64_i8(a_, b1_, aF, 0, 0, 0); \
  aG = __builtin_amdgcn_mfma_i32_16x16x64_i8(a_, b2_, aG, 0, 0, 0); \
  aO = __builtin_amdgcn_mfma_i32_16x16x64_i8(a_, b3_, aO, 0, 0, 0); \
} while (0)

__launch_bounds__(128, 1)
__global__ void k_lstm(const char* __restrict__ Uq, const float* __restrict__ su,
                       const unsigned short* __restrict__ xw,
                       const unsigned long long* __restrict__ mask64,
                       char* __restrict__ hseq, unsigned* __restrict__ flags,
                       float* __restrict__ hfin) {
  extern __shared__ char smem[];
  char* Us = smem;
  char* hs = smem + ULDS;   // [2 waves][16 rows][20]
  int tid = threadIdx.x, lane = tid & 63, hh = tid >> 6;
  int l15 = lane & 15, lq = lane >> 4;
  int grp = blockIdx.x >> 5, rank = blockIdx.x & 31;
  int m = hh * 16 + l15;    // hidden col within slice (0..31)

  // load U slice (i8) into padded LDS: 128 cols x 1024
  {
    const char* src = Uq + (size_t)rank * 131072;
    #pragma unroll 4
    for (int i = 0; i < 64; ++i) {
      int o = i * 2048 + tid * 16;
      int c = o >> 10, k = o & 1023;
      *(uint4*)(Us + c * UCOL + k) = *(const uint4*)(src + o);
    }
  }
  __syncthreads();

  float s0 = su[rank * 128 + 0 * 32 + m];
  float s1 = su[rank * 128 + 1 * 32 + m];
  float s2 = su[rank * 128 + 2 * 32 + m];
  float s3 = su[rank * 128 + 3 * 32 + m];
  int bo0 = (0 * 32 + m) * UCOL + lq * 16;
  int bo1 = (1 * 32 + m) * UCOL + lq * 16;
  int bo2 = (2 * 32 + m) * UCOL + lq * 16;
  int bo3 = (3 * 32 + m) * UCOL + lq * 16;

  float cst[4] = {0.f, 0.f, 0.f, 0.f};
  float hst[4] = {0.f, 0.f, 0.f, 0.f};

  const char* xb = (const char*)xw +
      ((size_t)(grp * 16 + lq * 4) * TT * FH + rank * 128 + m * 4) * 2;

  unsigned long long xg[4], xn[4];
  #pragma unroll
  for (int r = 0; r < 4; ++r) xg[r] = *(const unsigned long long*)(xb + (size_t)r * RSTRIDE);

  for (int t = 0; t < TT; ++t) {
    int tn = (t + 1) & 255;
    #pragma unroll
    for (int r = 0; r < 4; ++r)
      xn[r] = *(const unsigned long long*)(xb + (size_t)r * RSTRIDE + (size_t)tn * (FH * 2));
    unsigned long long mb = mask64[t];

    i32x4 aI = {0,0,0,0}, aF = {0,0,0,0}, aG = {0,0,0,0}, aO = {0,0,0,0};

    if (t > 0) {
      const unsigned* fl = flags + ((size_t)(t - 1) * 256 + grp * 64) * 16;
      const char* hp = hseq + (size_t)(t - 1) * 65536 + (size_t)(grp * 16 + l15) * 1024 + lq * 16;
      // ONE batched poll: lane covers flag `lane` (own 64B line)
      for (;;) {
        unsigned v = __hip_atomic_load(fl + (size_t)lane * 16,
                                       __ATOMIC_RELAXED, __HIP_MEMORY_SCOPE_AGENT);
        if (__all(v != 0)) break;
        __builtin_amdgcn_s_sleep(1);
      }
      asm volatile("" ::: "memory");
      uint4 A[16];
      #pragma unroll
      for (int u = 0; u < 16; ++u) A[u] = *(const uint4*)(hp + u * 64);
      #pragma unroll
      for (int u = 0; u < 16; ++u) { MFMA1(A[u], u); }
    }

    GATE(0); GATE(1); GATE(2); GATE(3);

    // pack wave's 16x16 i8 block and store (u32/lane) to the step buffer
    asm volatile("s_waitcnt lgkmcnt(0)" ::: "memory");
    {
      int prow = lane >> 2, pch = lane & 3;
      unsigned pv = *(const unsigned*)(hs + hh * 320 + prow * 20 + pch * 4);
      __hip_atomic_store(
          (unsigned*)(hseq + (size_t)t * 65536 + (size_t)(grp * 16 + prow) * 1024 +
                      rank * 32 + hh * 16 + pch * 4),
          pv, __ATOMIC_RELAXED, __HIP_MEMORY_SCOPE_AGENT);
    }
    asm volatile("s_waitcnt vmcnt(0)" ::: "memory");
    if (lane == 0)
      __hip_atomic_store(flags + ((size_t)t * 256 + grp * 64 + rank * 2 + hh) * 16, 1u,
                         __ATOMIC_RELAXED, __HIP_MEMORY_SCOPE_AGENT);

    xg[0] = xn[0]; xg[1] = xn[1]; xg[2] = xn[2]; xg[3] = xn[3];
  }
}

// ---------------- VAE head ----------------

__global__ void k_final(const float* __restrict__ hfin, const float* __restrict__ Wm,
                        const float* __restrict__ bm, const float* __restrict__ Wv,
                        const float* __restrict__ bv, const float* __restrict__ eps,
                        float* __restrict__ out) {
  int jb = blockIdx.x;
  int b = threadIdx.x & 63, u = threadIdx.x >> 6;
  int c0 = jb * 16 + u * 4;
  float am[4] = {0.f, 0.f, 0.f, 0.f};
  float av[4] = {0.f, 0.f, 0.f, 0.f};
  const float* hb = hfin + b * 1024;
  #pragma unroll 2
  for (int k = 0; k < 1024; ++k) {
    float hv = hb[k];
    float4 wm = *(const float4*)(Wm + (size_t)k * 1024 + c0);
    float4 wv = *(const float4*)(Wv + (size_t)k * 1024 + c0);
    am[0] += hv * wm.x; am[1] += hv * wm.y; am[2] += hv * wm.z; am[3] += hv * wm.w;
    av[0] += hv * wv.x; av[1] += hv * wv.y; av[2] += hv * wv.z; av[3] += hv * wv.w;
  }
  #pragma unroll
  for (int i = 0; i < 4; ++i) {
    int c = c0 + i;
    float mean = am[i] + bm[c];
    float lv = av[i] + bv[c];
    out[b * 1024 + c] = eps[b * 1024 + c] * __expf(0.5f * lv) + mean;
  }
}

// ---------------- launch ----------------

extern "C" void kernel_launch(void* const* d_in, const int* in_sizes, int n_in,
                              void* d_out, int out_size, void* d_ws, size_t ws_size,
                              hipStream_t stream) {
  const int*   tok = (const int*)d_in[0];
  const float* emb = (const float*)d_in[1];
  const float* W   = (const float*)d_in[2];
  const float* U   = (const float*)d_in[3];
  const float* bia = (const float*)d_in[4];
  const float* Wm  = (const float*)d_in[5];
  const float* bm  = (const float*)d_in[6];
  const float* Wv  = (const float*)d_in[7];
  const float* bv  = (const float*)d_in[8];
  const float* eps = (const float*)d_in[9];
  float* out = (float*)d_out;

  char* ws = (char*)d_ws;
  size_t off = 0;
  auto alloc = [&](size_t sz) { char* p = ws + off; off += (sz + 255) & ~(size_t)255; return p; };
  unsigned short* embb = (unsigned short*)alloc((size_t)VV * DD * 2);
  unsigned short* Wt   = (unsigned short*)alloc((size_t)FH * DD * 2);
  char*  Uq            = (char*)alloc((size_t)32 * 131072);
  float* su            = (float*)alloc((size_t)FH * 4);
  unsigned short* xw   = (unsigned short*)alloc((size_t)BB * TT * FH * 2);
  char*  hseq          = (char*)alloc((size_t)TT * 65536);
  unsigned* flags      = (unsigned*)alloc((size_t)TT * 256 * 64);
  unsigned long long* mask64 = (unsigned long long*)alloc((size_t)TT * 8);
  float* hfin          = (float*)alloc((size_t)BB * HH * 4);
  (void)in_sizes; (void)n_in; (void)out_size; (void)ws_size;

  (void)hipMemsetAsync(flags, 0, (size_t)TT * 256 * 64, stream);
  k_cast_emb<<<8000, 256, 0, stream>>>(emb, embb);
  k_prep_w<<<512, 256, 0, stream>>>(W, Wt);
  k_prep_uq<<<4096, 256, 0, stream>>>(U, Uq, su);
  k_mask<<<1, 256, 0, stream>>>(tok, mask64);
  k_gemm_xw<<<4096, 256, 0, stream>>>(tok, embb, Wt, bia, xw);
  (void)hipFuncSetAttribute((const void*)k_lstm, hipFuncAttributeMaxDynamicSharedMemorySize, LSTM_LDS);
  k_lstm<<<128, 128, LSTM_LDS, stream>>>(Uq, su, xw, mask64, hseq, flags, hfin);
  k_final<<<64, 256, 0, stream>>>(hfin, Wm, bm, Wv, bv, eps, out);
}

// Round 19
// 1572.160 us; speedup vs baseline: 1.3140x; 1.0022x over previous
//
#include <hip/hip_runtime.h>
#include <stdint.h>

#define BB 64
#define TT 256
#define VV 32000
#define DD 512
#define HH 1024
#define FH 4096

#define UCOL 1040                 // padded LDS col stride (i8, 1024+16)
#define ULDS (128 * UCOL)         // 133120
#define LSTM_LDS (ULDS + 1024)
#define RSTRIDE (TT * FH * 2)
#define QROW 1040

typedef float f32x4 __attribute__((ext_vector_type(4)));
typedef int   i32x4 __attribute__((ext_vector_type(4)));
typedef __bf16 bf16x8 __attribute__((ext_vector_type(8)));

typedef __attribute__((address_space(1))) void void_g;
typedef __attribute__((address_space(3))) void void_l;

static __device__ __forceinline__ void gload_lds16(const void* g, void* l) {
  __builtin_amdgcn_global_load_lds((const void_g*)g, (void_l*)l, 16, 0, 0);
}

static __device__ __forceinline__ unsigned short f2bf(float f) {
  union { float f; unsigned u; } x; x.f = f;
  unsigned r = x.u + 0x7FFFu + ((x.u >> 16) & 1u);
  return (unsigned short)(r >> 16);
}
static __device__ __forceinline__ float bf2f(unsigned short s) {
  union { unsigned u; float f; } x; x.u = ((unsigned)s) << 16;
  return x.f;
}
static __device__ __forceinline__ i32x4 as_i32x4(uint4 v) {
  union { uint4 u; i32x4 i; } x; x.u = v; return x.i;
}
static __device__ __forceinline__ float sigm(float x) {
  return 1.f / (1.f + __expf(-x));
}
static __device__ __forceinline__ float tanh_f(float x) {
  x = fminf(15.f, fmaxf(-15.f, x));
  float e = __expf(2.f * x);
  return (e - 1.f) / (e + 1.f);
}

// ---------------- prep kernels ----------------

__global__ void k_cast_emb(const float* __restrict__ src, unsigned short* __restrict__ dst) {
  size_t i = ((size_t)blockIdx.x * 256 + threadIdx.x) * 8;
  float4 a = *(const float4*)(src + i);
  float4 b = *(const float4*)(src + i + 4);
  uint4 o;
  o.x = (unsigned)f2bf(a.x) | ((unsigned)f2bf(a.y) << 16);
  o.y = (unsigned)f2bf(a.z) | ((unsigned)f2bf(a.w) << 16);
  o.z = (unsigned)f2bf(b.x) | ((unsigned)f2bf(b.y) << 16);
  o.w = (unsigned)f2bf(b.z) | ((unsigned)f2bf(b.w) << 16);
  *(uint4*)(dst + i) = o;
}

// LDS tile transpose: Wt[n][k] bf16. 64x64 tiles, coalesced read+write.
__launch_bounds__(256)
__global__ void k_prep_w(const float* __restrict__ Wsrc, unsigned short* __restrict__ Wt) {
  __shared__ float tile[64 * 68];
  int kb = blockIdx.x >> 6;     // k block (0..7)
  int nb = blockIdx.x & 63;     // n block (0..63)
  int tid = threadIdx.x;
  int r = tid >> 4;             // 0..15
  int c4 = (tid & 15) * 4;
  #pragma unroll
  for (int i = 0; i < 4; ++i) {
    int k = r + i * 16;
    float4 v = *(const float4*)(Wsrc + (size_t)(kb * 64 + k) * FH + nb * 64 + c4);
    *(float4*)&tile[k * 68 + c4] = v;
  }
  __syncthreads();
  int nr = tid >> 2;            // 0..63
  int kc = (tid & 3) * 16;      // 0,16,32,48
  unsigned o[8];
  #pragma unroll
  for (int h = 0; h < 8; ++h) {
    unsigned short e0 = f2bf(tile[(kc + 2 * h) * 68 + nr]);
    unsigned short e1 = f2bf(tile[(kc + 2 * h + 1) * 68 + nr]);
    o[h] = (unsigned)e0 | ((unsigned)e1 << 16);
  }
  uint4* dst = (uint4*)((char*)Wt + (size_t)(nb * 64 + nr) * 1024 + (size_t)(kb * 64 + kc) * 2);
  dst[0] = make_uint4(o[0], o[1], o[2], o[3]);
  dst[1] = make_uint4(o[4], o[5], o[6], o[7]);
}

// U int8 per-column quantization — COALESCED. Block = 64 n-cols x 1024 k.
// Pass 1: coalesced col-max; pass 2: re-read (L2-hot), quantize into padded
// LDS i8 tile; writeout 16B-coalesced per dest col.
// Dest: n -> g=n>>10, hid=n&1023, s=hid>>5, m=hid&31, c=g*32+m;
//       Uq[s][c][k], su[s*128+c]=maxcol/127^2.
__launch_bounds__(256)
__global__ void k_prep_uq(const float* __restrict__ Usrc, char* __restrict__ Uq,
                          float* __restrict__ su) {
  __shared__ char tile[64 * QROW];
  __shared__ float red[4 * 64];
  __shared__ float scl[64];
  int t = threadIdx.x;
  int nb = blockIdx.x;            // 0..63
  int n0 = nb * 64;
  int ct = t & 63;
  int kq = t >> 6;                // k quadrant (0..3)
  int n = n0 + ct;
  const float* src = Usrc + (size_t)kq * 256 * FH + n;
  float mx = 0.f;
  #pragma unroll 8
  for (int j = 0; j < 256; ++j)
    mx = fmaxf(mx, fabsf(src[(size_t)j * FH]));
  red[kq * 64 + ct] = mx;
  __syncthreads();
  if (kq == 0) {
    float m2 = fmaxf(fmaxf(red[ct], red[64 + ct]), fmaxf(red[128 + ct], red[192 + ct]));
    scl[ct] = m2 > 0.f ? 127.f / m2 : 0.f;
    int hid = n & 1023;
    int s = hid >> 5;
    int c = (n >> 10) * 32 + (hid & 31);
    su[s * 128 + c] = m2 / 16129.f;
  }
  __syncthreads();
  float inv = scl[ct];
  #pragma unroll 4
  for (int j = 0; j < 64; ++j) {
    unsigned pk = 0;
    #pragma unroll
    for (int e = 0; e < 4; ++e) {
      float v = src[(size_t)(j * 4 + e) * FH];
      int q = __float2int_rn(v * inv);
      pk |= ((unsigned)q & 255u) << (8 * e);
    }
    *(unsigned*)&tile[ct * QROW + kq * 256 + j * 4] = pk;
  }
  __syncthreads();
  int s0 = (n0 & 1023) >> 5;
  int gg = n0 >> 10;
  #pragma unroll
  for (int i = 0; i < 16; ++i) {
    int idx = t + i * 256;
    int col = idx >> 6;          // 0..63
    int ch  = idx & 63;          // 16B chunk
    int s = s0 + (col >> 5);
    int c = gg * 32 + (col & 31);
    uint4 v = *(const uint4*)&tile[col * QROW + ch * 16];
    *(uint4*)(Uq + (size_t)s * 131072 + (size_t)c * 1024 + ch * 16) = v;
  }
}

__global__ void k_mask(const int* __restrict__ tok, unsigned long long* __restrict__ mask64) {
  int t = threadIdx.x;
  unsigned long long m = 0;
  for (int b = 0; b < BB; ++b)
    m |= (unsigned long long)(tok[b * TT + t] != 0) << b;
  mask64[t] = m;
}

// ---------------- xW GEMM (gather fused) ----------------
// Output permuted: p = s*128 + m*4 + g  (4 gates adjacent per hidden)

__launch_bounds__(256)
__global__ void k_gemm_xw(const int* __restrict__ tok, const unsigned short* __restrict__ embb,
                          const unsigned short* __restrict__ Wt, const float* __restrict__ bsrc,
                          unsigned short* __restrict__ xw) {
  __shared__ char As[16384];
  __shared__ char Bs[16384];
  __shared__ int toks[128];
  int tid = threadIdx.x, lane = tid & 63, wid = tid >> 6;
  int bm = blockIdx.x >> 5, bn = blockIdx.x & 31;
  if (tid < 128) toks[tid] = tok[bm * 128 + tid];
  int wm = wid >> 1, wn = wid & 1;
  f32x4 vz = {0.f, 0.f, 0.f, 0.f};
  f32x4 acc[4][4];
  #pragma unroll
  for (int i = 0; i < 4; ++i)
    #pragma unroll
    for (int j = 0; j < 4; ++j) acc[i][j] = vz;

  int kls = (lane >> 4) * 16;
  for (int ks = 0; ks < 8; ++ks) {
    __syncthreads();
    #pragma unroll
    for (int c = 0; c < 4; ++c) {
      int o = wid * 4096 + c * 1024 + lane * 16;
      int m = o >> 7, kl = o & 127;
      const char* ga = (const char*)embb + (size_t)toks[m] * 1024 + ks * 128 + (kl ^ ((m & 7) << 4));
      gload_lds16(ga, As + o);
      const char* gb = (const char*)Wt + (size_t)(bn * 128 + m) * 1024 + ks * 128 + (kl ^ ((m & 7) << 4));
      gload_lds16(gb, Bs + o);
    }
    asm volatile("s_waitcnt vmcnt(0)" ::: "memory");
    __syncthreads();
    #pragma unroll
    for (int tk = 0; tk < 2; ++tk) {
      bf16x8 af[4], bf[4];
      int kb = tk * 64 + kls;
      #pragma unroll
      for (int mt = 0; mt < 4; ++mt) {
        int m = wm * 64 + mt * 16 + (lane & 15);
        af[mt] = *(const bf16x8*)(As + m * 128 + (kb ^ ((m & 7) << 4)));
      }
      #pragma unroll
      for (int nt = 0; nt < 4; ++nt) {
        int n = wn * 64 + nt * 16 + (lane & 15);
        bf[nt] = *(const bf16x8*)(Bs + n * 128 + (kb ^ ((n & 7) << 4)));
      }
      #pragma unroll
      for (int mt = 0; mt < 4; ++mt)
        #pragma unroll
        for (int nt = 0; nt < 4; ++nt)
          acc[mt][nt] = __builtin_amdgcn_mfma_f32_16x16x32_bf16(af[mt], bf[nt], acc[mt][nt], 0, 0, 0);
    }
  }
  #pragma unroll
  for (int nt = 0; nt < 4; ++nt) {
    int n = bn * 128 + wn * 64 + nt * 16 + (lane & 15);
    float bias = bsrc[n];
    int g = n >> 10, hid = n & 1023, s = hid >> 5, m = hid & 31;
    int p = s * 128 + m * 4 + g;
    #pragma unroll
    for (int mt = 0; mt < 4; ++mt) {
      #pragma unroll
      for (int r = 0; r < 4; ++r) {
        int row = bm * 128 + wm * 64 + mt * 16 + (lane >> 4) * 4 + r;
        xw[(size_t)row * FH + p] = f2bf(acc[mt][nt][r] + bias);
      }
    }
  }
}

// ---------------- persistent LSTM scan: 4 groups x 32 WGs ------------------
// Padded per-flag cache lines + single batched poll (lane = own flag line),
// then all 16 h-loads issue at once and 16 i8 MFMAs run.

#define GATE(R) do { \
  unsigned long long x_ = xg[R]; \
  float zi_ = (float)aI[R] * s0 + bf2f((unsigned short)(x_ & 0xFFFFu)); \
  float zf_ = (float)aF[R] * s1 + bf2f((unsigned short)((x_ >> 16) & 0xFFFFu)); \
  float zg_ = (float)aG[R] * s2 + bf2f((unsigned short)((x_ >> 32) & 0xFFFFu)); \
  float zo_ = (float)aO[R] * s3 + bf2f((unsigned short)((x_ >> 48) & 0xFFFFu)); \
  float I_ = sigm(zi_), F_ = sigm(zf_), G_ = tanh_f(zg_), O_ = sigm(zo_); \
  float cn_ = F_ * cst[R] + I_ * G_; \
  float hn_ = O_ * tanh_f(cn_); \
  if (!((mb >> (grp * 16 + lq * 4 + (R))) & 1ull)) { cn_ = cst[R]; hn_ = hst[R]; } \
  cst[R] = cn_; hst[R] = hn_; \
  hs[hh * 320 + (lq * 4 + (R)) * 20 + l15] = (char)__float2int_rn(hn_ * 127.f); \
  if (t == TT - 1) hfin[(size_t)(grp * 16 + lq * 4 + (R)) * 1024 + rank * 32 + hh * 16 + l15] = hn_; \
} while (0)

#define MFMA1(A, U) do { \
  i32x4 a_ = as_i32x4(A); \
  i32x4 b0_ = *(const i32x4*)(Us + bo0 + (U) * 64); \
  i32x4 b1_ = *(const i32x4*)(Us + bo1 + (U) * 64); \
  i32x4 b2_ = *(const i32x4*)(Us + bo2 + (U) * 64); \
  i32x4 b3_ = *(const i32x4*)(Us + bo3 + (U) * 64); \
  aI = __builtin_amdgcn_mfma_i32_16x16x64_i8(a_, b0_, aI, 0, 0, 0); \
  aF = __builtin_amdgcn_mfma_i32_16x16x64_i8(a_, b1_, aF, 0, 0, 0); \
  aG = __builtin_amdgcn_mfma_i32_16x16x64_i8(a_, b2_, aG, 0, 0, 0); \
  aO = __builtin_amdgcn_mfma_i32_16x16x64_i8(a_, b3_, aO, 0, 0, 0); \
} while (0)

__launch_bounds__(128, 1)
__global__ void k_lstm(const char* __restrict__ Uq, const float* __restrict__ su,
                       const unsigned short* __restrict__ xw,
                       const unsigned long long* __restrict__ mask64,
                       char* __restrict__ hseq, unsigned* __restrict__ flags,
                       float* __restrict__ hfin) {
  extern __shared__ char smem[];
  char* Us = smem;
  char* hs = smem + ULDS;   // [2 waves][16 rows][20]
  int tid = threadIdx.x, lane = tid & 63, hh = tid >> 6;
  int l15 = lane & 15, lq = lane >> 4;
  int grp = blockIdx.x >> 5, rank = blockIdx.x & 31;
  int m = hh * 16 + l15;    // hidden col within slice (0..31)

  // load U slice (i8) into padded LDS: 128 cols x 1024
  {
    const char* src = Uq + (size_t)rank * 131072;
    #pragma unroll 4
    for (int i = 0; i < 64; ++i) {
      int o = i * 2048 + tid * 16;
      int c = o >> 10, k = o & 1023;
      *(uint4*)(Us + c * UCOL + k) = *(const uint4*)(src + o);
    }
  }
  __syncthreads();

  float s0 = su[rank * 128 + 0 * 32 + m];
  float s1 = su[rank * 128 + 1 * 32 + m];
  float s2 = su[rank * 128 + 2 * 32 + m];
  float s3 = su[rank * 128 + 3 * 32 + m];
  int bo0 = (0 * 32 + m) * UCOL + lq * 16;
  int bo1 = (1 * 32 + m) * UCOL + lq * 16;
  int bo2 = (2 * 32 + m) * UCOL + lq * 16;
  int bo3 = (3 * 32 + m) * UCOL + lq * 16;

  float cst[4] = {0.f, 0.f, 0.f, 0.f};
  float hst[4] = {0.f, 0.f, 0.f, 0.f};

  const char* xb = (const char*)xw +
      ((size_t)(grp * 16 + lq * 4) * TT * FH + rank * 128 + m * 4) * 2;

  unsigned long long xg[4], xn[4];
  #pragma unroll
  for (int r = 0; r < 4; ++r) xg[r] = *(const unsigned long long*)(xb + (size_t)r * RSTRIDE);

  for (int t = 0; t < TT; ++t) {
    int tn = (t + 1) & 255;
    #pragma unroll
    for (int r = 0; r < 4; ++r)
      xn[r] = *(const unsigned long long*)(xb + (size_t)r * RSTRIDE + (size_t)tn * (FH * 2));
    unsigned long long mb = mask64[t];

    i32x4 aI = {0,0,0,0}, aF = {0,0,0,0}, aG = {0,0,0,0}, aO = {0,0,0,0};

    if (t > 0) {
      const unsigned* fl = flags + ((size_t)(t - 1) * 256 + grp * 64) * 16;
      const char* hp = hseq + (size_t)(t - 1) * 65536 + (size_t)(grp * 16 + l15) * 1024 + lq * 16;
      // ONE batched poll: lane covers flag `lane` (own 64B line)
      for (;;) {
        unsigned v = __hip_atomic_load(fl + (size_t)lane * 16,
                                       __ATOMIC_RELAXED, __HIP_MEMORY_SCOPE_AGENT);
        if (__all(v != 0)) break;
        __builtin_amdgcn_s_sleep(1);
      }
      asm volatile("" ::: "memory");
      uint4 A[16];
      #pragma unroll
      for (int u = 0; u < 16; ++u) A[u] = *(const uint4*)(hp + u * 64);
      #pragma unroll
      for (int u = 0; u < 16; ++u) { MFMA1(A[u], u); }
    }

    GATE(0); GATE(1); GATE(2); GATE(3);

    // pack wave's 16x16 i8 block and store (u32/lane) to the step buffer
    asm volatile("s_waitcnt lgkmcnt(0)" ::: "memory");
    {
      int prow = lane >> 2, pch = lane & 3;
      unsigned pv = *(const unsigned*)(hs + hh * 320 + prow * 20 + pch * 4);
      __hip_atomic_store(
          (unsigned*)(hseq + (size_t)t * 65536 + (size_t)(grp * 16 + prow) * 1024 +
                      rank * 32 + hh * 16 + pch * 4),
          pv, __ATOMIC_RELAXED, __HIP_MEMORY_SCOPE_AGENT);
    }
    asm volatile("s_waitcnt vmcnt(0)" ::: "memory");
    if (lane == 0)
      __hip_atomic_store(flags + ((size_t)t * 256 + grp * 64 + rank * 2 + hh) * 16, 1u,
                         __ATOMIC_RELAXED, __HIP_MEMORY_SCOPE_AGENT);

    xg[0] = xn[0]; xg[1] = xn[1]; xg[2] = xn[2]; xg[3] = xn[3];
  }
}

// ---------------- VAE head ----------------

__global__ void k_final(const float* __restrict__ hfin, const float* __restrict__ Wm,
                        const float* __restrict__ bm, const float* __restrict__ Wv,
                        const float* __restrict__ bv, const float* __restrict__ eps,
                        float* __restrict__ out) {
  int jb = blockIdx.x;
  int b = threadIdx.x & 63, u = threadIdx.x >> 6;
  int c0 = jb * 16 + u * 4;
  float am[4] = {0.f, 0.f, 0.f, 0.f};
  float av[4] = {0.f, 0.f, 0.f, 0.f};
  const float* hb = hfin + b * 1024;
  #pragma unroll 2
  for (int k = 0; k < 1024; ++k) {
    float hv = hb[k];
    float4 wm = *(const float4*)(Wm + (size_t)k * 1024 + c0);
    float4 wv = *(const float4*)(Wv + (size_t)k * 1024 + c0);
    am[0] += hv * wm.x; am[1] += hv * wm.y; am[2] += hv * wm.z; am[3] += hv * wm.w;
    av[0] += hv * wv.x; av[1] += hv * wv.y; av[2] += hv * wv.z; av[3] += hv * wv.w;
  }
  #pragma unroll
  for (int i = 0; i < 4; ++i) {
    int c = c0 + i;
    float mean = am[i] + bm[c];
    float lv = av[i] + bv[c];
    out[b * 1024 + c] = eps[b * 1024 + c] * __expf(0.5f * lv) + mean;
  }
}

// ---------------- launch ----------------

extern "C" void kernel_launch(void* const* d_in, const int* in_sizes, int n_in,
                              void* d_out, int out_size, void* d_ws, size_t ws_size,
                              hipStream_t stream) {
  const int*   tok = (const int*)d_in[0];
  const float* emb = (const float*)d_in[1];
  const float* W   = (const float*)d_in[2];
  const float* U   = (const float*)d_in[3];
  const float* bia = (const float*)d_in[4];
  const float* Wm  = (const float*)d_in[5];
  const float* bm  = (const float*)d_in[6];
  const float* Wv  = (const float*)d_in[7];
  const float* bv  = (const float*)d_in[8];
  const float* eps = (const float*)d_in[9];
  float* out = (float*)d_out;

  char* ws = (char*)d_ws;
  size_t off = 0;
  auto alloc = [&](size_t sz) { char* p = ws + off; off += (sz + 255) & ~(size_t)255; return p; };
  unsigned short* embb = (unsigned short*)alloc((size_t)VV * DD * 2);
  unsigned short* Wt   = (unsigned short*)alloc((size_t)FH * DD * 2);
  char*  Uq            = (char*)alloc((size_t)32 * 131072);
  float* su            = (float*)alloc((size_t)FH * 4);
  unsigned short* xw   = (unsigned short*)alloc((size_t)BB * TT * FH * 2);
  char*  hseq          = (char*)alloc((size_t)TT * 65536);
  unsigned* flags      = (unsigned*)alloc((size_t)TT * 256 * 64);
  unsigned long long* mask64 = (unsigned long long*)alloc((size_t)TT * 8);
  float* hfin          = (float*)alloc((size_t)BB * HH * 4);
  (void)in_sizes; (void)n_in; (void)out_size; (void)ws_size;

  (void)hipMemsetAsync(flags, 0, (size_t)TT * 256 * 64, stream);
  k_cast_emb<<<8000, 256, 0, stream>>>(emb, embb);
  k_prep_w<<<512, 256, 0, stream>>>(W, Wt);
  k_prep_uq<<<64, 256, 0, stream>>>(U, Uq, su);
  k_mask<<<1, 256, 0, stream>>>(tok, mask64);
  k_gemm_xw<<<4096, 256, 0, stream>>>(tok, embb, Wt, bia, xw);
  (void)hipFuncSetAttribute((const void*)k_lstm, hipFuncAttributeMaxDynamicSharedMemorySize, LSTM_LDS);
  k_lstm<<<128, 128, LSTM_LDS, stream>>>(Uq, su, xw, mask64, hseq, flags, hfin);
  k_final<<<64, 256, 0, stream>>>(hfin, Wm, bm, Wv, bv, eps, out);
}